// Round 1
// baseline (103.226 us; speedup 1.0000x reference)
//
#include <hip/hip_runtime.h>
#include <math.h>

#define NB 4096

// ---- workspace layout ----
// ints:
#define LEAFo  0               // 3 barriers * 8 leaves * 32 ints (128B spacing)
#define MASTo  768             // 3 * 32
#define RELo   864             // 8 * 32 spread release lines
#define GHo    1120            // 4*4096 histogram (low 16b: count, high 16b: scatter cursor)
#define MEMSET_BYTES 70016     // 17504 ints
// floats:
#define VGo    17504           // B*4096*64
#define ASo    1066080         // sorted a
#define PERMo  1082464         // int
#define Po     1098848         // chunk partials [b][64ch][192]
#define PSEAo  1148000         // [b][64]
#define PSAo   1148256         // [b][64]

__device__ __forceinline__ void gst(float* p, float v) {
    __hip_atomic_store(p, v, __ATOMIC_RELAXED, __HIP_MEMORY_SCOPE_AGENT);
}
__device__ __forceinline__ void gsti(int* p, int v) {
    __hip_atomic_store(p, v, __ATOMIC_RELAXED, __HIP_MEMORY_SCOPE_AGENT);
}

__device__ __forceinline__ int bucket_of(float v) {
    int k = (int)((v + 16.0f) * 128.0f);
    k = k < 0 ? 0 : k;
    k = k > (NB - 1) ? (NB - 1) : k;
    return k;
}

// Tree-arrival barrier (validated R9): 32 contenders/leaf, 8 leaves/master,
// release on 8 spread lines. Grid stays 256 blocks so this is unchanged.
__device__ __forceinline__ void gbar(int* wsi, int idx) {
    __syncthreads();
    if (threadIdx.x == 0) {
        int leaf = blockIdx.x & 7;
        bool bcast = false;
        int old = __hip_atomic_fetch_add(wsi + LEAFo + (idx * 8 + leaf) * 32, 1,
                                         __ATOMIC_RELAXED, __HIP_MEMORY_SCOPE_AGENT);
        if (old == 31) {
            int m = __hip_atomic_fetch_add(wsi + MASTo + idx * 32, 1,
                                           __ATOMIC_RELAXED, __HIP_MEMORY_SCOPE_AGENT);
            if (m == 7) {
#pragma unroll
                for (int i = 0; i < 8; i++)
                    __hip_atomic_store(wsi + RELo + i * 32, idx + 1,
                                       __ATOMIC_RELAXED, __HIP_MEMORY_SCOPE_AGENT);
                bcast = true;
            }
        }
        if (!bcast) {
            const int* myrel = wsi + RELo + leaf * 32;
            while (__hip_atomic_load(myrel, __ATOMIC_RELAXED, __HIP_MEMORY_SCOPE_AGENT) <= idx)
                __builtin_amdgcn_s_sleep(1);
        }
    }
    __syncthreads();
}

// 1024 threads/block (16 waves = 4 waves/SIMD) instead of 256 (1 wave/SIMD):
// the kernel is latency-bound (VALUBusy 7%, HBM 4%, occ 10%); 4x TLP + 4x
// shorter per-thread chains attack the exposed-latency regime directly.
__global__ __launch_bounds__(1024, 1) void k_fused(
        const float* __restrict__ x,
        const float* __restrict__ Wq, const float* __restrict__ bq,
        const float* __restrict__ Wk, const float* __restrict__ bk,
        const float* __restrict__ wcq, const float* __restrict__ wck,
        const float* __restrict__ Wv, const float* __restrict__ bv,
        const float* __restrict__ Wg, const float* __restrict__ bg,
        float* __restrict__ ws, float* __restrict__ out) {
    __shared__ float smem[13824];       // 55.3 KB
    int tid = threadIdx.x;
    int bid = blockIdx.x;
    int b = bid >> 6, t6 = bid & 63;
    int* wsi = (int*)ws;

    float myA = 0.f, myD = 0.f;         // a,d for pixel t6*64+tid (tid<64)
    int   myQ = 0;                      // snapped split chunk for own column j

    // ===== Phase A: weight prep (redundant) + projections + histogram =====
    {
        float* xt  = smem;              // [64][72] = 4608
        float* wt  = smem + 4608;       // [64][72]: wt[c][o] = Wvg[o][c]
        float* wgT = smem + 9216;       // [64][65]: wgT[m*65+o] = Wg[o][m] (padded)
        float* wqe = smem + 13376, *wke = smem + 13440, *bvg = smem + 13504, *misc = smem + 13568;
        // 1) x tile prefetch into registers (HBM latency overlaps Wg staging)
        const float4* xb4 = (const float4*)(x + (size_t)b * 64 * 4096);
        float4 xr;
        {
            int c = tid >> 4, nl4 = tid & 15;
            xr = xb4[c * 1024 + t6 * 16 + nl4];
        }
        // 2) stage Wg transposed into LDS (coalesced global read, padded LDS writes)
        {
            const float4* wg4 = (const float4*)Wg;
            int o = tid >> 4, q4 = tid & 15;
            float4 g = wg4[tid];
            int m0 = q4 * 4;
            wgT[(m0 + 0) * 65 + o] = g.x; wgT[(m0 + 1) * 65 + o] = g.y;
            wgT[(m0 + 2) * 65 + o] = g.z; wgT[(m0 + 3) * 65 + o] = g.w;
        }
        if (tid < 64) {
            float s1 = 0.f, s2 = 0.f;
            for (int o = 0; o < 16; o++) { s1 += wcq[o] * Wq[o * 64 + tid]; s2 += wck[o] * Wk[o * 64 + tid]; }
            wqe[tid] = s1; wke[tid] = s2;
        } else if (tid == 64) {
            float s = 0.f; for (int o = 0; o < 16; o++) s += wcq[o] * bq[o]; misc[0] = s;
        } else if (tid == 65) {
            float s = 0.f; for (int o = 0; o < 16; o++) s += wck[o] * bk[o]; misc[1] = s;
        }
        // 3) store x tile to LDS
        {
            int c = tid >> 4, nl4 = tid & 15;
            *(float4*)&xt[c * 72 + nl4 * 4] = xr;
        }
        __syncthreads();
        // 4) Wvg = Wg @ Wv from LDS-transposed Wg (conflict-free) + Wv broadcast
        {
            int o = tid & 63, c0 = (tid >> 6) * 4;
            float acc[4];
#pragma unroll
            for (int k = 0; k < 4; k++) acc[k] = 0.f;
            for (int m = 0; m < 64; m++) {
                float wg = wgT[m * 65 + o];
                float4 a0 = *(const float4*)(Wv + m * 64 + c0);   // wave-uniform -> broadcast
                acc[0] += wg * a0.x; acc[1] += wg * a0.y; acc[2] += wg * a0.z; acc[3] += wg * a0.w;
            }
#pragma unroll
            for (int k = 0; k < 4; k++) wt[(c0 + k) * 72 + o] = acc[k];
        }
        // bvg = Wg @ bv from the LDS transpose (was uncoalesced global rows);
        // ready before the next __syncthreads, first used after it.
        if (tid < 64) {
            float s3 = 0.f;
            for (int m = 0; m < 64; m++) s3 += wgT[m * 65 + tid] * bv[m];
            bvg[tid] = s3;
        }
        __syncthreads();
        if (tid < 64) {
            float s1 = misc[0], s2 = misc[1];
            for (int c = 0; c < 64; c++) {
                float xv = xt[c * 72 + tid];
                s1 += wqe[c] * xv; s2 += wke[c] * xv;
            }
            myA = s1; myD = s2;                              // both stay in registers
            atomicAdd(&wsi[GHo + b * 4096 + bucket_of(s1)], 1);
        }
        {
            int o = tid & 63, nl0 = (tid >> 6) * 4;
            float acc[4];
            float bo = bvg[o];
#pragma unroll
            for (int k = 0; k < 4; k++) acc[k] = bo;
            for (int c = 0; c < 64; c++) {
                float wv = wt[c * 72 + o];
                const float* xr2 = &xt[c * 72 + nl0];
#pragma unroll
                for (int k = 0; k < 4; k++) acc[k] += wv * xr2[k];
            }
#pragma unroll
            for (int k = 0; k < 4; k++)
                gst(&ws[VGo + ((size_t)(b * 4096) + t6 * 64 + nl0 + k) * 64 + o], acc[k]);
        }
    }
    gbar(wsi, 0);

    // ===== Phase B: per-block shfl scan + scatter + own-column split lookup =====
    {
        unsigned int* hist = (unsigned int*)smem;          // [4096] bucket starts
        unsigned int* wtot = hist + 4096;                  // [16]
        int* gh_b = wsi + GHo + b * 4096;
#pragma unroll 4
        for (int i = tid; i < NB; i += 1024) hist[i] = (unsigned int)gh_b[i] & 0xFFFFu;  // cached
        __syncthreads();
        int lane = tid & 63, w = tid >> 6;
        unsigned int s = 0u; int base = tid * 4;
#pragma unroll
        for (int k = 0; k < 4; k++) s += hist[base + k];
        unsigned int inc = s;
        for (int off = 1; off < 64; off <<= 1) {
            unsigned int u = __shfl_up(inc, off);
            if (lane >= off) inc += u;
        }
        if (lane == 63) wtot[w] = inc;
        __syncthreads();
        unsigned int run = inc - s;
        for (int w2 = 0; w2 < w; w2++) run += wtot[w2];
        for (int k = 0; k < 4; k++) {
            unsigned int h = hist[base + k];
            hist[base + k] = run;       // hist now holds bucket starts
            run += h;
        }
        __syncthreads();
        if (tid < 64) {
            // split lookup for own output column j = t6*64+tid (d in register)
            myQ = ((int)hist[bucket_of(-myD)] + 32) >> 6;
            // scatter own pixel; cursor packed in GH high bits
            int i = t6 * 64 + tid;
            int kb = bucket_of(myA);
            int old = atomicAdd(&gh_b[kb], 0x10000);
            int r = (int)hist[kb] + (old >> 16);
            gst(&ws[ASo + b * 4096 + r], myA);
            gsti((int*)ws + PERMo + b * 4096 + r, i);
        }
    }
    gbar(wsi, 1);

    // ===== Phase C: chunk partials (cached reads, sc writes), 16 warps x 4 rows =====
    {
        int c = tid & 63, w = tid >> 6;
        int r0 = t6 * 64 + w * 4;
        const int* perm = (const int*)ws + PERMo;
        int pk[4]; float avs[4], wvs[4];
#pragma unroll
        for (int k = 0; k < 4; k++) pk[k] = perm[b * 4096 + r0 + k];
#pragma unroll
        for (int k = 0; k < 4; k++) avs[k] = ws[ASo + b * 4096 + r0 + k];
#pragma unroll
        for (int k = 0; k < 4; k++) wvs[k] = ws[VGo + ((size_t)(b * 4096) + pk[k]) * 64 + c];
        float s1 = 0.f, s2 = 0.f, s3 = 0.f, sea_w = 0.f, sa_w = 0.f;
#pragma unroll
        for (int k = 0; k < 4; k++) {
            float ea = expf(avs[k]);
            s1 += wvs[k]; s2 += wvs[k] * ea; s3 += wvs[k] * avs[k];
            sea_w += ea; sa_w += avs[k];
        }
        float* partL = smem;            // [16][3][64] = 3072
        float* wsc   = smem + 3072;     // [32]
        partL[(w * 3 + 0) * 64 + c] = s1;
        partL[(w * 3 + 1) * 64 + c] = s2;
        partL[(w * 3 + 2) * 64 + c] = s3;
        if (c == 0) { wsc[w] = sea_w; wsc[16 + w] = sa_w; }
        __syncthreads();
        if (tid < 192) {
            int g = tid >> 6, cc = tid & 63;
            float sum = 0.f;
#pragma unroll
            for (int ww = 0; ww < 16; ww++) sum += partL[(ww * 3 + g) * 64 + cc];
            gst(&ws[Po + (b * 64 + t6) * 192 + tid], sum);
        } else if (tid == 192) {
            float sum = 0.f;
#pragma unroll
            for (int ww = 0; ww < 16; ww++) sum += wsc[ww];
            gst(&ws[PSEAo + b * 64 + t6], sum);
        } else if (tid == 193) {
            float sum = 0.f;
#pragma unroll
            for (int ww = 0; ww < 16; ww++) sum += wsc[16 + ww];
            gst(&ws[PSAo + b * 64 + t6], sum);
        }
    }
    gbar(wsi, 2);

    // ===== Phase F: per-block chunk-prefix (reg prefetch) + output =====
    {
        float* CP     = smem;                  // [65][193] = 12545
        float* cpsea  = smem + 12545;          // [65]
        float* cpsa   = smem + 12610;          // [65]
        float* djs    = smem + 12675;          // [64]
        float* edjs   = smem + 12739;          // [64]
        float* invden = smem + 12803;          // [64]
        int*   qarr   = (int*)(smem + 12867);  // [64]
        float* bgs    = smem + 12931;          // [64]
        if (tid < 192) {
            float v[64];
#pragma unroll
            for (int ch = 0; ch < 64; ch++) v[ch] = ws[Po + b * 12288 + ch * 192 + tid]; // cached
            float r = 0.f;
#pragma unroll
            for (int q = 0; q < 64; q++) { CP[q * 193 + tid] = r; r += v[q]; }
            CP[64 * 193 + tid] = r;
        } else if (tid == 192) {
            float v[64];
#pragma unroll
            for (int ch = 0; ch < 64; ch++) v[ch] = ws[PSEAo + b * 64 + ch];
            float r = 0.f;
#pragma unroll
            for (int q = 0; q < 64; q++) { cpsea[q] = r; r += v[q]; }
            cpsea[64] = r;
        } else if (tid == 193) {
            float v[64];
#pragma unroll
            for (int ch = 0; ch < 64; ch++) v[ch] = ws[PSAo + b * 64 + ch];
            float r = 0.f;
#pragma unroll
            for (int q = 0; q < 64; q++) { cpsa[q] = r; r += v[q]; }
            cpsa[64] = r;
        }
        if (tid < 64) bgs[tid] = bg[tid];
        __syncthreads();
        int j0 = t6 * 64;
        if (tid < 64) {
            float dj = myD;
            float edj = expf(dj);
            int q = myQ;
            float den = 1.5f * ((cpsa[64] - cpsa[q]) + dj * (float)(4096 - 64 * q)
                                - (float)(64 * q) + edj * cpsea[q]);
            qarr[tid] = q; djs[tid] = dj; edjs[tid] = edj; invden[tid] = 1.0f / den;
        }
        __syncthreads();
        {
            int jl = tid & 63, cq = tid >> 6;
            float dj = djs[jl], edj = edjs[jl], inv = invden[jl];
            int qb = qarr[jl] * 193;
#pragma unroll
            for (int cc = cq; cc < 64; cc += 16) {
                float c1 = CP[qb + cc], c2 = CP[qb + 64 + cc], c3 = CP[qb + 128 + cc];
                float t1 = CP[64 * 193 + cc], t3 = CP[64 * 193 + 128 + cc];
                float num = (t3 - c3) + dj * t1 - (1.0f + dj) * c1 + edj * c2;
                out[((size_t)(b * 64 + cc)) * 4096 + j0 + jl] = num * inv + bgs[cc];
            }
        }
    }
}

extern "C" void kernel_launch(void* const* d_in, const int* in_sizes, int n_in,
                              void* d_out, int out_size, void* d_ws, size_t ws_size,
                              hipStream_t stream) {
    const float* x   = (const float*)d_in[0];
    const float* Wq  = (const float*)d_in[1];
    const float* bq  = (const float*)d_in[2];
    const float* Wk  = (const float*)d_in[3];
    const float* bk  = (const float*)d_in[4];
    const float* wcq = (const float*)d_in[5];
    const float* wck = (const float*)d_in[6];
    const float* Wv  = (const float*)d_in[7];
    const float* bv  = (const float*)d_in[8];
    const float* Wg  = (const float*)d_in[9];
    const float* bg  = (const float*)d_in[10];
    float* ws  = (float*)d_ws;
    float* out = (float*)d_out;

    hipMemsetAsync(d_ws, 0, MEMSET_BYTES, stream);
    k_fused<<<256, 1024, 0, stream>>>(x, Wq, bq, Wk, bk, wcq, wck, Wv, bv, Wg, bg, ws, out);
}